// Round 15
// baseline (320.600 us; speedup 1.0000x reference)
//
#include <hip/hip_runtime.h>
#include <hip/hip_bf16.h>
#include <climits>

#define NATOMS 50000
#define NEDGES 100000
#define AD 64
#define BD 16
#define PITCH 1096            // LDS row pitch in bf16 elems (1088 + 8)
#define NR ((NEDGES + 31) / 32)   // 3125 windows: wave u owns [fb(32u), fb(32u+32))
#define NBANDS 256
#define NWAVES 16             // 1024 thr; 12-13 windows/band -> 1 window/wave

typedef __bf16 bf16x8 __attribute__((ext_vector_type(8)));
typedef __bf16 bf16x4 __attribute__((ext_vector_type(4)));
typedef float  f32x16 __attribute__((ext_vector_type(16)));

// Dual first_break: smallest break index >= p0 and >= p1, loads overlapped.
// Break: q==0, q==NEDGES, or tgt[q]!=tgt[q-1].
__device__ __forceinline__ void first_break2(const int* __restrict__ pair,
                                             int p0, int p1, const int lane,
                                             int& s, int& e) {
    const int qa = p0 + lane;
    const int qb = p1 + lane;
    const bool ba = (qa == 0 || qa >= NEDGES) ? true : (pair[2 * qa] != pair[2 * qa - 2]);
    const bool bb = (qb == 0 || qb >= NEDGES) ? true : (pair[2 * qb] != pair[2 * qb - 2]);
    const unsigned long long ma = __ballot(ba);
    const unsigned long long mb = __ballot(bb);

    if (ma) { s = p0 + (int)__builtin_ctzll(ma); if (s > NEDGES) s = NEDGES; }
    else {
        int p = p0 + 64;
        while (true) {
            const int q = p + lane;
            const bool bk = (q >= NEDGES) ? true : (pair[2 * q] != pair[2 * q - 2]);
            const unsigned long long m = __ballot(bk);
            if (m) { s = p + (int)__builtin_ctzll(m); if (s > NEDGES) s = NEDGES; break; }
            p += 64;
        }
    }
    if (mb) { e = p1 + (int)__builtin_ctzll(mb); if (e > NEDGES) e = NEDGES; }
    else {
        int p = p1 + 64;
        while (true) {
            const int q = p + lane;
            const bool bk = (q >= NEDGES) ? true : (pair[2 * q] != pair[2 * q - 2]);
            const unsigned long long m = __ballot(bk);
            if (m) { e = p + (int)__builtin_ctzll(m); if (e > NEDGES) e = NEDGES; break; }
            p += 64;
        }
    }
}

// zero cols [half*32, half*32+32) of rows [a0, a1)
__device__ __forceinline__ void zero_rows(float* __restrict__ out,
                                          int a0, int a1, const int half) {
    const float4 z = make_float4(0.f, 0.f, 0.f, 0.f);
    for (int a = a0; a < a1; ++a) {
        float4* o = reinterpret_cast<float4*>(out + (long)a * AD + half * 32);
        #pragma unroll
        for (int rq = 0; rq < 8; ++rq) o[rq] = z;
    }
}

// MFMA + in-wave segmented inclusive scan over chunk [g, g+32) ∩ [, e).
// ni / myTgt precomputed by the caller (lane's edge = g + l31, clamped).
// C[feature][edge], edge = l31; acc0 = features 0..31, acc1 = 32..63,
// f = (r&3)+8*(r>>2)+4*half (+32 for acc1).
__device__ __forceinline__ void scan_slot(
    const int g, const int e, const int ni, const int myTgt,
    const float* __restrict__ atom, const float* __restrict__ bond,
    const __bf16* __restrict__ Brow0, const __bf16* __restrict__ Brow1,
    const int l31, const int half, const int h8,
    f32x16& acc0, f32x16& acc1, bool& isLast)
{
    const int eA = g + l31;
    const bool validE = (eA < e);
    const int eAc = validE ? eA : 0;

    const float* nbrRow  = atom + (long)ni * AD;
    const float* bondRow = bond + (long)eAc * BD;

    // half-row of nbr this lane needs: j = 16q + 8*half + r
    // (invalid lanes' garbage is never consumed: tgt=INT_MAX never matches)
    float nb[4][8];
    #pragma unroll
    for (int q = 0; q < 4; ++q) {
        const float4 lo = *reinterpret_cast<const float4*>(nbrRow + q * 16 + h8);
        const float4 hi = *reinterpret_cast<const float4*>(nbrRow + q * 16 + h8 + 4);
        nb[q][0] = lo.x; nb[q][1] = lo.y; nb[q][2] = lo.z; nb[q][3] = lo.w;
        nb[q][4] = hi.x; nb[q][5] = hi.y; nb[q][6] = hi.z; nb[q][7] = hi.w;
    }
    float bd[16];
    #pragma unroll
    for (int q = 0; q < 4; ++q) {
        const float4 v = *reinterpret_cast<const float4*>(bondRow + q * 4);
        bd[q * 4 + 0] = v.x; bd[q * 4 + 1] = v.y;
        bd[q * 4 + 2] = v.z; bd[q * 4 + 3] = v.w;
    }

    #pragma unroll
    for (int r = 0; r < 16; ++r) { acc0[r] = 0.f; acc1[r] = 0.f; }

    // main K: k = 16t + 8*half + r ; b = t>>2 ; j = 16*(t&3) + 8*half + r
    // ONE a-fragment feeds BOTH feature-half MFMAs.
    #pragma unroll
    for (int t = 0; t < 64; ++t) {
        const float bv = bd[t >> 2];
        bf16x8 a;
        #pragma unroll
        for (int r = 0; r < 8; ++r) a[r] = (__bf16)(bv * nb[t & 3][r]);
        const int k0 = t * 16 + h8;
        const bf16x8 b0 = *reinterpret_cast<const bf16x8*>(Brow0 + k0);
        const bf16x8 b1 = *reinterpret_cast<const bf16x8*>(Brow1 + k0);
        acc0 = __builtin_amdgcn_mfma_f32_32x32x16_bf16(b0, a, acc0, 0, 0, 0);
        acc1 = __builtin_amdgcn_mfma_f32_32x32x16_bf16(b1, a, acc1, 0, 0, 0);
    }
    #pragma unroll
    for (int t = 64; t < 68; ++t) {   // bias rows, A-side vector = nbr
        bf16x8 a;
        #pragma unroll
        for (int r = 0; r < 8; ++r) a[r] = (__bf16)(nb[t - 64][r]);
        const int k0 = t * 16 + h8;
        const bf16x8 b0 = *reinterpret_cast<const bf16x8*>(Brow0 + k0);
        const bf16x8 b1 = *reinterpret_cast<const bf16x8*>(Brow1 + k0);
        acc0 = __builtin_amdgcn_mfma_f32_32x32x16_bf16(b0, a, acc0, 0, 0, 0);
        acc1 = __builtin_amdgcn_mfma_f32_32x32x16_bf16(b1, a, acc1, 0, 0, 0);
    }

    // segmented inclusive scan over sorted tgt within the 32-lane group.
    // Steps 1,2,4 always; steps 8,16 only if some segment length >= 9.
    #pragma unroll
    for (int d = 1; d <= 4; d <<= 1) {
        const int srcTgt = __shfl_up(myTgt, (unsigned)d, 32);
        const bool same = (l31 >= d) && (srcTgt == myTgt);
        #pragma unroll
        for (int r = 0; r < 16; ++r) {
            const float v0 = __shfl_up(acc0[r], (unsigned)d, 32);
            const float v1 = __shfl_up(acc1[r], (unsigned)d, 32);
            if (same) { acc0[r] += v0; acc1[r] += v1; }
        }
    }
    const int src8 = __shfl_up(myTgt, 8u, 32);
    if (__any((l31 >= 8) && (src8 == myTgt))) {
        const bool same8 = (l31 >= 8) && (src8 == myTgt);
        #pragma unroll
        for (int r = 0; r < 16; ++r) {
            const float v0 = __shfl_up(acc0[r], 8u, 32);
            const float v1 = __shfl_up(acc1[r], 8u, 32);
            if (same8) { acc0[r] += v0; acc1[r] += v1; }
        }
        const int src16 = __shfl_up(myTgt, 16u, 32);
        const bool same16 = (l31 >= 16) && (src16 == myTgt);
        #pragma unroll
        for (int r = 0; r < 16; ++r) {
            const float v0 = __shfl_up(acc0[r], 16u, 32);
            const float v1 = __shfl_up(acc1[r], 16u, 32);
            if (same16) { acc0[r] += v0; acc1[r] += v1; }
        }
    }

    const int nTgt = __shfl_down(myTgt, 1u, 32);
    isLast = validE && ((l31 == 31) || (nTgt != myTgt));
}

__device__ __forceinline__ void store_row(float* __restrict__ o, const int half,
                                          const f32x16& a0, const f32x16& a1) {
    #pragma unroll
    for (int rq = 0; rq < 4; ++rq) {
        float4 v0, v1;
        v0.x = a0[rq*4+0]; v0.y = a0[rq*4+1]; v0.z = a0[rq*4+2]; v0.w = a0[rq*4+3];
        v1.x = a1[rq*4+0]; v1.y = a1[rq*4+1]; v1.z = a1[rq*4+2]; v1.w = a1[rq*4+3];
        *reinterpret_cast<float4*>(o + 8 * rq + 4 * half)      = v0;
        *reinterpret_cast<float4*>(o + 32 + 8 * rq + 4 * half) = v1;
    }
}

__global__ __launch_bounds__(64 * NWAVES, 1)
void edgenet_kernel(const float* __restrict__ atom,
                    const float* __restrict__ bond,
                    const int*   __restrict__ pair,
                    const float* __restrict__ kern,
                    const float* __restrict__ bias,
                    float* __restrict__ out)
{
    __shared__ __bf16 Blds[64 * PITCH];     // full B [i][k], 140 KB
    __shared__ float  Crow[NWAVES][64];     // per-wave chunk1->chunk2 carry (same-wave DS order, no barrier)

    const int tid  = threadIdx.x;
    const int band = blockIdx.x;
    const int NT   = 64 * NWAVES;

    const int wave = tid >> 6;
    const int lane = tid & 63;
    const int l31  = lane & 31;
    const int half = lane >> 5;
    const int h8   = half * 8;

    // ---- stage B = [kernel | bias] into LDS as bf16 ----
    for (int q = tid; q < (16 * 4096) / 4; q += NT) {
        const int idx = q * 4;                  // flat: b*4096 + i*64 + j
        const int b = idx >> 12;
        const int i = (idx >> 6) & 63;
        const int j = idx & 63;
        const float4 v = *reinterpret_cast<const float4*>(kern + idx);
        bf16x4 w;
        w[0] = (__bf16)v.x; w[1] = (__bf16)v.y; w[2] = (__bf16)v.z; w[3] = (__bf16)v.w;
        *reinterpret_cast<bf16x4*>(Blds + i * PITCH + (b << 6) + j) = w;
    }
    {   // bias: exactly 1024 quads
        const int q = tid;
        const int idx = q * 4;
        const int i = idx >> 6;
        const int j = idx & 63;
        const float4 v = *reinterpret_cast<const float4*>(bias + idx);
        bf16x4 w;
        w[0] = (__bf16)v.x; w[1] = (__bf16)v.y; w[2] = (__bf16)v.z; w[3] = (__bf16)v.w;
        *reinterpret_cast<bf16x4*>(Blds + i * PITCH + 1024 + j) = w;
    }

    // ---- pre-barrier: window bounds + pair prefetch (4 regs live; no spill risk).
    // Wave u owns [fb(32u), fb(32u+32)) — these ranges PARTITION the edge list
    // (boundaries are breaks), so no segment crosses waves: zero handoff.
    const int uBase = (NR * band) / NBANDS;
    const int uEnd  = (NR * (band + 1)) / NBANDS;
    const int u = uBase + wave;

    int s = 0, ext = 0, ni = 0, myTgt = INT_MAX;
    bool active = false;
    if (u < uEnd) {
        const int p0 = 32 * u;
        int p1 = p0 + 32; if (p1 > NEDGES) p1 = NEDGES;
        first_break2(pair, p0, p1, lane, s, ext);
        if (s < ext) {
            active = true;
            const int e1 = (s + 32 < ext) ? s + 32 : ext;
            const int eA = s + l31;
            const bool v = (eA < e1);
            const int eAc = v ? eA : 0;
            int nl = pair[2 * eAc + 1];
            if ((unsigned)nl >= NATOMS) nl = 0;
            ni = nl;
            myTgt = v ? pair[2 * eA] : INT_MAX;
        }
    }

    __syncthreads();   // the ONLY barrier in the kernel

    if (!active) return;

    const __bf16* __restrict__ Brow0 = Blds + l31 * PITCH;         // features 0..31
    const __bf16* __restrict__ Brow1 = Blds + (32 + l31) * PITCH;  // features 32..63

    const int e1 = (s + 32 < ext) ? s + 32 : ext;   // chunk1 end
    const int w1 = e1 - s;
    // chunk2 exists iff the tail segment overhangs s+32. Since s >= 32u, all
    // breaks in (s, ext) are < 32u+32 <= s+32, so chunk2 is break-free
    // (single segment) and its width = ext-s-32 <= max segment length < 32.
    const bool cont = (ext > s + 32);

    f32x16 acc0, acc1;
    bool isLast;
    scan_slot(s, e1, ni, myTgt, atom, bond, Brow0, Brow1,
              l31, half, h8, acc0, acc1, isLast);

    // ---- fused zeroing of gap rows (atoms with no incoming edges). All
    // segment STARTS of this window lie in chunk1; the seg-first lane
    // exclusively owns the gap before its segment.
    if (l31 < w1) {
        const int pTgt = __shfl_up(myTgt, 1u, 32);
        const bool segFirst = (l31 == 0) || (pTgt != myTgt);
        if (segFirst) {
            const int prevEdgeTgt = (l31 > 0) ? pTgt
                                  : ((s > 0) ? pair[2 * (s - 1)] : -1);
            if (prevEdgeTgt + 1 < myTgt)
                zero_rows(out, prevEdgeTgt + 1, myTgt, half);
        }
        // tail gap after the globally last edge (chunk1-resident case;
        // cont implies NEDGES-1 > s+31 so no collision)
        if (s + l31 == NEDGES - 1 && myTgt + 1 < NATOMS)
            zero_rows(out, myTgt + 1, NATOMS, half);
    }

    // ---- emit chunk1 owners (suppress the continuing tail lane) ----
    if (isLast && !(cont && (l31 == 31)))
        store_row(out + (long)myTgt * AD, half, acc0, acc1);

    // ---- rare overhang chunk2 (wave-uniform branch, single segment) ----
    if (cont) {
        // stash chunk1 tail partial in this wave's Crow (lane 31, both halves)
        if (l31 == 31) {
            #pragma unroll
            for (int r = 0; r < 16; ++r) {
                const int f = (r & 3) + 8 * (r >> 2) + 4 * half;
                Crow[wave][f]      = acc0[r];
                Crow[wave][32 + f] = acc1[r];
            }
        }
        const int g2 = s + 32;
        const int eA2 = g2 + l31;
        const bool v2 = (eA2 < ext);
        const int eAc2 = v2 ? eA2 : 0;
        int ni2 = pair[2 * eAc2 + 1];
        if ((unsigned)ni2 >= NATOMS) ni2 = 0;
        const int tg2 = v2 ? pair[2 * eA2] : INT_MAX;

        bool isLast2;
        scan_slot(g2, ext, ni2, tg2, atom, bond, Brow0, Brow1,
                  l31, half, h8, acc0, acc1, isLast2);

        if (isLast2) {   // single owner lane per half (uniform tgt in chunk2)
            // same-wave DS write->read: in-order DS pipe, no barrier needed
            #pragma unroll
            for (int r = 0; r < 16; ++r) {
                const int f = (r & 3) + 8 * (r >> 2) + 4 * half;
                acc0[r] += Crow[wave][f];
                acc1[r] += Crow[wave][32 + f];
            }
            store_row(out + (long)tg2 * AD, half, acc0, acc1);
            if (ext == NEDGES && tg2 + 1 < NATOMS)
                zero_rows(out, tg2 + 1, NATOMS, half);
        }
    }
}

extern "C" void kernel_launch(void* const* d_in, const int* in_sizes, int n_in,
                              void* d_out, int out_size, void* d_ws, size_t ws_size,
                              hipStream_t stream) {
    const float* atom = (const float*)d_in[0];
    const float* bond = (const float*)d_in[1];
    const int*   pair = (const int*)d_in[2];
    const float* kern = (const float*)d_in[3];
    const float* bias = (const float*)d_in[4];
    float* out = (float*)d_out;

    // no memset: gap rows zeroed in-kernel; covered rows owner-written
    edgenet_kernel<<<NBANDS, 64 * NWAVES, 0, stream>>>(atom, bond, pair, kern, bias, out);
}

// Round 16
// 36.494 us; speedup vs baseline: 8.7850x; 8.7850x over previous
//
#include <hip/hip_runtime.h>
#include <hip/hip_bf16.h>
#include <climits>

#define NATOMS 50000
#define NEDGES 100000
#define AD 64
#define BD 16
#define PITCH 1096            // LDS row pitch in bf16 elems (1088 + 8)
#define NR ((NEDGES + 31) / 32)   // 3125 aligned 32-edge windows
#define NBANDS 256
#define NWAVES 16             // 1024 thr; nW <= 14 windows/band -> 1 window/wave

typedef __bf16 bf16x8 __attribute__((ext_vector_type(8)));
typedef __bf16 bf16x4 __attribute__((ext_vector_type(4)));
typedef float  f32x16 __attribute__((ext_vector_type(16)));

// Dual first_break: smallest break index >= p0 and >= p1, loads overlapped.
// Break: q==0, q==NEDGES, or tgt[q]!=tgt[q-1].
__device__ __forceinline__ void first_break2(const int* __restrict__ pair,
                                             int p0, int p1, const int lane,
                                             int& s, int& e) {
    const int qa = p0 + lane;
    const int qb = p1 + lane;
    const bool ba = (qa == 0 || qa >= NEDGES) ? true : (pair[2 * qa] != pair[2 * qa - 2]);
    const bool bb = (qb == 0 || qb >= NEDGES) ? true : (pair[2 * qb] != pair[2 * qb - 2]);
    const unsigned long long ma = __ballot(ba);
    const unsigned long long mb = __ballot(bb);

    if (ma) { s = p0 + (int)__builtin_ctzll(ma); if (s > NEDGES) s = NEDGES; }
    else {
        int p = p0 + 64;
        while (true) {
            const int q = p + lane;
            const bool bk = (q >= NEDGES) ? true : (pair[2 * q] != pair[2 * q - 2]);
            const unsigned long long m = __ballot(bk);
            if (m) { s = p + (int)__builtin_ctzll(m); if (s > NEDGES) s = NEDGES; break; }
            p += 64;
        }
    }
    if (mb) { e = p1 + (int)__builtin_ctzll(mb); if (e > NEDGES) e = NEDGES; }
    else {
        int p = p1 + 64;
        while (true) {
            const int q = p + lane;
            const bool bk = (q >= NEDGES) ? true : (pair[2 * q] != pair[2 * q - 2]);
            const unsigned long long m = __ballot(bk);
            if (m) { e = p + (int)__builtin_ctzll(m); if (e > NEDGES) e = NEDGES; break; }
            p += 64;
        }
    }
}

// zero cols [half*32, half*32+32) of rows [a0, a1)
__device__ __forceinline__ void zero_rows(float* __restrict__ out,
                                          int a0, int a1, const int half) {
    const float4 z = make_float4(0.f, 0.f, 0.f, 0.f);
    for (int a = a0; a < a1; ++a) {
        float4* o = reinterpret_cast<float4*>(out + (long)a * AD + half * 32);
        #pragma unroll
        for (int rq = 0; rq < 8; ++rq) o[rq] = z;
    }
}

// MFMA + in-wave segmented inclusive scan over window [g, g+32) ∩ [, e).
// ni / myTgt precomputed by the caller (pre-barrier prefetch).
// C[feature][edge], edge = l31; acc0 = features 0..31, acc1 = 32..63,
// f = (r&3)+8*(r>>2)+4*half (+32 for acc1).
__device__ __forceinline__ void scan_slot(
    const int g, const int e, const int ni, const int myTgt,
    const float* __restrict__ atom, const float* __restrict__ bond,
    const __bf16* __restrict__ Brow0, const __bf16* __restrict__ Brow1,
    const int l31, const int half, const int h8,
    f32x16& acc0, f32x16& acc1, bool& isLast)
{
    const int eA = g + l31;
    const bool validE = (eA < e);
    const int eAc = validE ? eA : 0;

    const float* nbrRow  = atom + (long)ni * AD;
    const float* bondRow = bond + (long)eAc * BD;

    // half-row of nbr this lane needs: j = 16q + 8*half + r
    // (invalid lanes' garbage is never consumed: tgt=INT_MAX never matches)
    float nb[4][8];
    #pragma unroll
    for (int q = 0; q < 4; ++q) {
        const float4 lo = *reinterpret_cast<const float4*>(nbrRow + q * 16 + h8);
        const float4 hi = *reinterpret_cast<const float4*>(nbrRow + q * 16 + h8 + 4);
        nb[q][0] = lo.x; nb[q][1] = lo.y; nb[q][2] = lo.z; nb[q][3] = lo.w;
        nb[q][4] = hi.x; nb[q][5] = hi.y; nb[q][6] = hi.z; nb[q][7] = hi.w;
    }
    float bd[16];
    #pragma unroll
    for (int q = 0; q < 4; ++q) {
        const float4 v = *reinterpret_cast<const float4*>(bondRow + q * 4);
        bd[q * 4 + 0] = v.x; bd[q * 4 + 1] = v.y;
        bd[q * 4 + 2] = v.z; bd[q * 4 + 3] = v.w;
    }

    #pragma unroll
    for (int r = 0; r < 16; ++r) { acc0[r] = 0.f; acc1[r] = 0.f; }

    // main K: k = 16t + 8*half + r ; b = t>>2 ; j = 16*(t&3) + 8*half + r
    // ONE a-fragment feeds BOTH feature-half MFMAs.
    #pragma unroll
    for (int t = 0; t < 64; ++t) {
        const float bv = bd[t >> 2];
        bf16x8 a;
        #pragma unroll
        for (int r = 0; r < 8; ++r) a[r] = (__bf16)(bv * nb[t & 3][r]);
        const int k0 = t * 16 + h8;
        const bf16x8 b0 = *reinterpret_cast<const bf16x8*>(Brow0 + k0);
        const bf16x8 b1 = *reinterpret_cast<const bf16x8*>(Brow1 + k0);
        acc0 = __builtin_amdgcn_mfma_f32_32x32x16_bf16(b0, a, acc0, 0, 0, 0);
        acc1 = __builtin_amdgcn_mfma_f32_32x32x16_bf16(b1, a, acc1, 0, 0, 0);
    }
    #pragma unroll
    for (int t = 64; t < 68; ++t) {   // bias rows, A-side vector = nbr
        bf16x8 a;
        #pragma unroll
        for (int r = 0; r < 8; ++r) a[r] = (__bf16)(nb[t - 64][r]);
        const int k0 = t * 16 + h8;
        const bf16x8 b0 = *reinterpret_cast<const bf16x8*>(Brow0 + k0);
        const bf16x8 b1 = *reinterpret_cast<const bf16x8*>(Brow1 + k0);
        acc0 = __builtin_amdgcn_mfma_f32_32x32x16_bf16(b0, a, acc0, 0, 0, 0);
        acc1 = __builtin_amdgcn_mfma_f32_32x32x16_bf16(b1, a, acc1, 0, 0, 0);
    }

    // segmented inclusive scan over sorted tgt within the 32-lane group.
    // Steps 1,2,4 always; steps 8,16 only if some segment length >= 9.
    #pragma unroll
    for (int d = 1; d <= 4; d <<= 1) {
        const int srcTgt = __shfl_up(myTgt, (unsigned)d, 32);
        const bool same = (l31 >= d) && (srcTgt == myTgt);
        #pragma unroll
        for (int r = 0; r < 16; ++r) {
            const float v0 = __shfl_up(acc0[r], (unsigned)d, 32);
            const float v1 = __shfl_up(acc1[r], (unsigned)d, 32);
            if (same) { acc0[r] += v0; acc1[r] += v1; }
        }
    }
    const int src8 = __shfl_up(myTgt, 8u, 32);
    if (__any((l31 >= 8) && (src8 == myTgt))) {
        const bool same8 = (l31 >= 8) && (src8 == myTgt);
        #pragma unroll
        for (int r = 0; r < 16; ++r) {
            const float v0 = __shfl_up(acc0[r], 8u, 32);
            const float v1 = __shfl_up(acc1[r], 8u, 32);
            if (same8) { acc0[r] += v0; acc1[r] += v1; }
        }
        const int src16 = __shfl_up(myTgt, 16u, 32);
        const bool same16 = (l31 >= 16) && (src16 == myTgt);
        #pragma unroll
        for (int r = 0; r < 16; ++r) {
            const float v0 = __shfl_up(acc0[r], 16u, 32);
            const float v1 = __shfl_up(acc1[r], 16u, 32);
            if (same16) { acc0[r] += v0; acc1[r] += v1; }
        }
    }

    const int nTgt = __shfl_down(myTgt, 1u, 32);
    isLast = validE && ((l31 == 31) || (nTgt != myTgt));
}

__global__ __launch_bounds__(64 * NWAVES, 1)
void edgenet_kernel(const float* __restrict__ atom,
                    const float* __restrict__ bond,
                    const int*   __restrict__ pair,
                    const float* __restrict__ kern,
                    const float* __restrict__ bias,
                    float* __restrict__ out)
{
    __shared__ __bf16 Blds[64 * PITCH];     // full B [i][k], 140 KB
    __shared__ float  Trow[NWAVES][64];     // per-window continuing tail partials
    __shared__ int    Ttag[NWAVES];         // tgt tag (INT_MIN = no continuation)

    const int tid  = threadIdx.x;
    const int band = blockIdx.x;
    const int NT   = 64 * NWAVES;

    const int wave = tid >> 6;
    const int lane = tid & 63;
    const int l31  = lane & 31;
    const int half = lane >> 5;
    const int h8   = half * 8;

    // ---- stage B = [kernel | bias] into LDS as bf16 ----
    for (int q = tid; q < (16 * 4096) / 4; q += NT) {
        const int idx = q * 4;                  // flat: b*4096 + i*64 + j
        const int b = idx >> 12;
        const int i = (idx >> 6) & 63;
        const int j = idx & 63;
        const float4 v = *reinterpret_cast<const float4*>(kern + idx);
        bf16x4 w;
        w[0] = (__bf16)v.x; w[1] = (__bf16)v.y; w[2] = (__bf16)v.z; w[3] = (__bf16)v.w;
        *reinterpret_cast<bf16x4*>(Blds + i * PITCH + (b << 6) + j) = w;
    }
    {   // bias: exactly 1024 quads
        const int q = tid;
        const int idx = q * 4;
        const int i = idx >> 6;
        const int j = idx & 63;
        const float4 v = *reinterpret_cast<const float4*>(bias + idx);
        bf16x4 w;
        w[0] = (__bf16)v.x; w[1] = (__bf16)v.y; w[2] = (__bf16)v.z; w[3] = (__bf16)v.w;
        *reinterpret_cast<bf16x4*>(Blds + i * PITCH + 1024 + j) = w;
    }

    // ---- pre-barrier: band bounds + this wave's ni/myTgt prefetch
    //      (sB,eB,ni,myTgt = 4 ints live across the barrier; no spill risk)
    const int r0 = (NR * band) / NBANDS;
    const int r1 = (NR * (band + 1)) / NBANDS;
    int sB, eB;
    first_break2(pair, 32 * r0, 32 * r1, lane, sB, eB);

    const int g    = sB + 32 * wave;
    const int gEnd = (g + 32 < eB) ? (g + 32) : eB;
    const bool active = (g < eB);
    const int wW = active ? (gEnd - g) : 0;

    int ni = 0, myTgt = INT_MAX;
    if (active) {
        const int eA = g + l31;
        const bool v = (eA < gEnd);
        const int eAc = v ? eA : 0;
        int nl = pair[2 * eAc + 1];
        if ((unsigned)nl >= NATOMS) nl = 0;
        ni = nl;
        myTgt = v ? pair[2 * eA] : INT_MAX;
    }

    __syncthreads();   // staging complete

    const __bf16* __restrict__ Brow0 = Blds + l31 * PITCH;         // features 0..31
    const __bf16* __restrict__ Brow1 = Blds + (32 + l31) * PITCH;  // features 32..63

    f32x16 acc0, acc1;
    bool isLast = false;

    if (active) {
        scan_slot(g, gEnd, ni, myTgt, atom, bond, Brow0, Brow1,
                  l31, half, h8, acc0, acc1, isLast);
    }

    // continuation into next window? (tail lanes l31==31 only; truncated
    // windows have g+32 >= eB so contin=false automatically)
    bool myContin = false;
    if (active && (l31 == 31) && (g + 32 < eB)) {
        myContin = (myTgt == pair[2 * (g + 32)]);
    }

    // tail lanes of continuing windows stash their window-partial row
    if (myContin) {
        #pragma unroll
        for (int r = 0; r < 16; ++r) {
            const int f = (r & 3) + 8 * (r >> 2) + 4 * half;
            Trow[wave][f]      = acc0[r];
            Trow[wave][32 + f] = acc1[r];
        }
    }
    if (lane == 31) Ttag[wave] = myContin ? myTgt : INT_MIN;   // also inactive waves

    __syncthreads();   // Trow/Ttag published

    const bool validE = (l31 < wW);

    // ---- fused zeroing of gap rows (atoms with no incoming edges). ----
    // Windows tile the edge range contiguously (across waves AND bands), so
    // the seg-FIRST lane of each segment exclusively owns the gap before it.
    if (active && validE) {
        const int pTgt = __shfl_up(myTgt, 1u, 32);
        const bool segFirst = (l31 == 0) || (pTgt != myTgt);
        if (segFirst) {
            const int prevEdgeTgt = (l31 > 0) ? pTgt
                                  : ((g > 0) ? pair[2 * (g - 1)] : -1);
            // continuation windows: prevEdgeTgt == myTgt -> empty range
            if (prevEdgeTgt + 1 < myTgt)
                zero_rows(out, prevEdgeTgt + 1, myTgt, half);
        }
        // tail gap after the globally last edge
        if (g + l31 == NEDGES - 1 && myTgt + 1 < NATOMS)
            zero_rows(out, myTgt + 1, NATOMS, half);
    }

    // ---- emit owned segments ----
    if (active && isLast && !myContin) {
        // merge tails from earlier windows covered by my segment
        for (int w2 = wave - 1; w2 >= 0; --w2) {
            if (Ttag[w2] != myTgt) break;
            #pragma unroll
            for (int r = 0; r < 16; ++r) {
                const int f = (r & 3) + 8 * (r >> 2) + 4 * half;
                acc0[r] += Trow[w2][f];
                acc1[r] += Trow[w2][32 + f];
            }
        }
        float* o = out + (long)myTgt * AD;
        #pragma unroll
        for (int rq = 0; rq < 4; ++rq) {
            float4 v0, v1;
            v0.x = acc0[rq*4+0]; v0.y = acc0[rq*4+1]; v0.z = acc0[rq*4+2]; v0.w = acc0[rq*4+3];
            v1.x = acc1[rq*4+0]; v1.y = acc1[rq*4+1]; v1.z = acc1[rq*4+2]; v1.w = acc1[rq*4+3];
            *reinterpret_cast<float4*>(o + 8 * rq + 4 * half)      = v0;
            *reinterpret_cast<float4*>(o + 32 + 8 * rq + 4 * half) = v1;
        }
    }
}

extern "C" void kernel_launch(void* const* d_in, const int* in_sizes, int n_in,
                              void* d_out, int out_size, void* d_ws, size_t ws_size,
                              hipStream_t stream) {
    const float* atom = (const float*)d_in[0];
    const float* bond = (const float*)d_in[1];
    const int*   pair = (const int*)d_in[2];
    const float* kern = (const float*)d_in[3];
    const float* bias = (const float*)d_in[4];
    float* out = (float*)d_out;

    // no memset: gap rows are zeroed in-kernel; covered rows are owner-written
    edgenet_kernel<<<NBANDS, 64 * NWAVES, 0, stream>>>(atom, bond, pair, kern, bias, out);
}